// Round 4
// baseline (202.951 us; speedup 1.0000x reference)
//
#include <hip/hip_runtime.h>
#include <math.h>

#define HH 1024
#define WW 1024
#define NPLANES 12              // B*C = 4*3
#define PLANE (HH * WW)
#define NTOT (NPLANES * PLANE)  // 12,582,912

// ---- Kernel A tile (chain + blur + LCE) ----
#define TW 64
#define TH 64
#define HRA 78                  // TH + 14
#define RAWP 84                 // raw pitch (80 cols used), 336B rows keep 16B align
#define HBLP 68                 // hbl pitch

// ---- Kernel B tile (blur + softness + gradient) ----
#define TH2 128
#define HRB 142                 // TH2 + 14

struct W15 { float w[15]; };

// zero-padded aligned float4 row load (x must be multiple of 4)
__device__ inline float4 ld4z(const float* __restrict__ row, int x) {
    if (x >= 0 && x + 3 < WW) return *(const float4*)(row + x);
    float4 r; float* p = (float*)&r;
#pragma unroll
    for (int j = 0; j < 4; ++j) { int xx = x + j; p[j] = (xx >= 0 && xx < WW) ? row[xx] : 0.0f; }
    return r;
}

__device__ inline float chain1(float t, float gain, float gamma, float sb,
                               float hr, float br, float ct) {
    t = t * gain;
    t = __builtin_amdgcn_exp2f(gamma * __log2f(t));          // pow, t>=0
    float hi = __fdividef(1.0f, 1.0f + __expf((0.5f - t) * 10.0f));
    t = t + sb * (1.0f - hi) - hr * hi;
    t = fminf(fmaxf(t, 0.0f), 1.0f);
    t = ct * (t - 0.5f) + 0.5f + br;
    return fminf(fmaxf(t, 0.0f), 1.0f);
}

// ============ Kernel A: pointwise chain + separable blur + local contrast =====
// dst = (1+e)*t0 - e*blur15(t0),  t0 = chain(x), zero-padded blur on t0
__global__ __launch_bounds__(256) void k_chain_blur_lce(
    const float* __restrict__ x, float* __restrict__ dst,
    const float* __restrict__ gains,
    const float* __restrict__ pg, const float* __restrict__ psb,
    const float* __restrict__ phr, const float* __restrict__ pbr,
    const float* __restrict__ pct, const float* __restrict__ penh, W15 wk)
{
    __shared__ float raw[HRA * RAWP];   // chained input (halo incl.), 26.2 KB
    __shared__ float hbl[HRA * HBLP];   // h-blurred, 21.2 KB
    const int p   = blockIdx.z;
    const int x0  = blockIdx.x * TW;
    const int y0  = blockIdx.y * TH;
    const int tid = threadIdx.x;
    const float* plane = x + (size_t)p * PLANE;

    const float gain  = gains[p % 3];
    const float gamma = *pg, sb = *psb, hr = *phr, br = *pbr, ct = *pct;
    const float e     = *penh;

    // ---- P0: chain(x) -> raw LDS (each element chained exactly once) --------
    for (int i = tid; i < HRA * 20; i += 256) {
        int r  = i / 20;                 // 0..77
        int c4 = i % 20;                 // float4 col chunk, 0..19
        int y  = y0 - 7 + r;
        int xb = x0 - 8 + c4 * 4;        // multiple of 4
        float4 v;
        if (y >= 0 && y < HH) {
            float4 f = ld4z(plane + (size_t)y * WW, xb);
            float* pf = (float*)&f; float* pv = (float*)&v;
#pragma unroll
            for (int j = 0; j < 4; ++j) {
                float cv = chain1(pf[j], gain, gamma, sb, hr, br, ct);
                int xx = xb + j;
                pv[j] = (xx >= 0 && xx < WW) ? cv : 0.0f;   // conv zero-padding
            }
        } else {
            v = make_float4(0.0f, 0.0f, 0.0f, 0.0f);
        }
        *(float4*)&raw[r * RAWP + c4 * 4] = v;
    }
    __syncthreads();

    // ---- P1: horizontal 15-tap from raw -> hbl ------------------------------
    {
        const int c4 = (tid & 15) * 4;   // 0..60
        const int r0 = tid >> 4;         // 0..15
#pragma unroll
        for (int it = 0; it < 5; ++it) {
            int r = r0 + 16 * it;
            if (r < HRA) {
                float f[20];
#pragma unroll
                for (int m = 0; m < 5; ++m)
                    *(float4*)&f[4 * m] = *(const float4*)&raw[r * RAWP + c4 + 4 * m];
                float4 o; float* po = (float*)&o;
#pragma unroll
                for (int j = 0; j < 4; ++j) {
                    float acc = 0.0f;
#pragma unroll
                    for (int k = 0; k < 15; ++k) acc += wk.w[k] * f[j + 1 + k];
                    po[j] = acc;
                }
                *(float4*)&hbl[r * HBLP + c4] = o;
            }
        }
    }
    __syncthreads();

    // ---- P2: vertical 15-tap + LCE (center from raw LDS) --------------------
    const int tx  = tid & 63;
    const int ty  = tid >> 6;            // 4 row-chunks of 16
    const int ly0 = ty * 16;

    float win[15];
#pragma unroll
    for (int k = 0; k < 15; ++k) win[k] = hbl[(ly0 + k) * HBLP + tx];

    float* dstP = dst + (size_t)p * PLANE;
#pragma unroll
    for (int j = 0; j < 16; ++j) {
        int y = y0 + ly0 + j;
        float lm = 0.0f;
#pragma unroll
        for (int k = 0; k < 15; ++k) lm += wk.w[k] * win[k];
        float c = raw[(ly0 + j + 7) * RAWP + tx + 8];      // chained center
        dstP[(size_t)y * WW + x0 + tx] = (1.0f + e) * c - e * lm;
#pragma unroll
        for (int k = 0; k < 14; ++k) win[k] = win[k + 1];
        win[14] = hbl[(ly0 + j + 15) * HBLP + tx];
    }
}

// ============ Kernel B: separable blur + softness + gradient mask + clip ======
__global__ __launch_bounds__(256) void k_blur_final(
    const float* __restrict__ src, float* __restrict__ dst,
    const float* __restrict__ psoft, const float* __restrict__ pint,
    const float* __restrict__ prot, const float* __restrict__ phard, W15 wk)
{
    __shared__ float hbl[HRB * HBLP];   // 38.6 KB
    const int p   = blockIdx.z;
    const int x0  = blockIdx.x * TW;
    const int y0  = blockIdx.y * TH2;
    const int tid = threadIdx.x;
    const float* plane = src + (size_t)p * PLANE;

    // ---- P1: horizontal blur from global -> LDS (registers only) ------------
    {
        const int c4 = (tid & 15) * 4;
        const int r0 = tid >> 4;
#pragma unroll
        for (int it = 0; it < 9; ++it) {
            int r = r0 + 16 * it;
            if (r < HRB) {
                int y = y0 - 7 + r;
                float4 o;
                if (y >= 0 && y < HH) {
                    const float* row = plane + (size_t)y * WW;
                    int xb = x0 + c4 - 8;
                    float f[20];
                    *(float4*)&f[0]  = ld4z(row, xb);
                    *(float4*)&f[4]  = ld4z(row, xb + 4);
                    *(float4*)&f[8]  = ld4z(row, xb + 8);
                    *(float4*)&f[12] = ld4z(row, xb + 12);
                    *(float4*)&f[16] = ld4z(row, xb + 16);
                    float* po = (float*)&o;
#pragma unroll
                    for (int j = 0; j < 4; ++j) {
                        float acc = 0.0f;
#pragma unroll
                        for (int k = 0; k < 15; ++k) acc += wk.w[k] * f[j + 1 + k];
                        po[j] = acc;
                    }
                } else {
                    o = make_float4(0.0f, 0.0f, 0.0f, 0.0f);
                }
                *(float4*)&hbl[r * HBLP + c4] = o;
            }
        }
    }
    __syncthreads();

    // ---- P2: vertical blur + softness mix + rotated gradient + clip ---------
    const int tx  = tid & 63;
    const int ty  = tid >> 6;
    const int ly0 = ty * 32;             // 4 chunks of 32 rows
    const int x   = x0 + tx;

    const float s     = *psoft;
    const float inten = *pint;
    const float hard  = *phard;
    const float theta = (*prot) * 0.017453292519943295f;
    const float cth = __cosf(theta), sth = __sinf(theta);
    const float base = (-1.0f + 2.0f * (float)x * (1.0f / (float)(WW - 1))) * cth;

    float win[15];
#pragma unroll
    for (int k = 0; k < 15; ++k) win[k] = hbl[(ly0 + k) * HBLP + tx];

    float* dstP = dst + (size_t)p * PLANE;
#pragma unroll
    for (int j = 0; j < 32; ++j) {
        int y = y0 + ly0 + j;
        float bl = 0.0f;
#pragma unroll
        for (int k = 0; k < 15; ++k) bl += wk.w[k] * win[k];
        float c = plane[(size_t)y * WW + x];               // x2 center (L2-hot)
        float v = s * bl + (1.0f - s) * c;
        float gy = -1.0f + 2.0f * (float)y * (1.0f / (float)(HH - 1));
        float mask = __fdividef(1.0f, 1.0f + __expf(hard * (base + gy * sth)));
        v = v * (1.0f - inten * mask);
        v = fminf(fmaxf(v, 0.0f), 1.0f);
        dstP[(size_t)y * WW + x] = v;
#pragma unroll
        for (int k = 0; k < 14; ++k) win[k] = win[k + 1];
        win[14] = hbl[(ly0 + j + 15) * HBLP + tx];
    }
}

extern "C" void kernel_launch(void* const* d_in, const int* in_sizes, int n_in,
                              void* d_out, int out_size, void* d_ws, size_t ws_size,
                              hipStream_t stream)
{
    const float* x       = (const float*)d_in[0];
    const float* gains   = (const float*)d_in[1];
    const float* p_gamma = (const float*)d_in[2];
    const float* p_sb    = (const float*)d_in[3];
    const float* p_hr    = (const float*)d_in[4];
    const float* p_br    = (const float*)d_in[5];
    const float* p_ct    = (const float*)d_in[6];
    const float* p_enh   = (const float*)d_in[7];
    const float* p_soft  = (const float*)d_in[8];
    const float* p_int   = (const float*)d_in[9];
    const float* p_rot   = (const float*)d_in[10];
    const float* p_hard  = (const float*)d_in[11];

    float* X2  = (float*)d_ws;    // x2 intermediate (50.3 MB)
    float* OUT = (float*)d_out;

    W15 wk;
    {
        double g[15], sum = 0.0;
        for (int i = 0; i < 15; ++i) { double d = (double)(i - 7); g[i] = exp(-d * d / 18.0); sum += g[i]; }
        for (int i = 0; i < 15; ++i) wk.w[i] = (float)(g[i] / sum);
    }

    // Kernel A: x -> X2   (chain + blur + local contrast, all in one)
    dim3 ga(WW / TW, HH / TH, NPLANES);      // 16 x 16 x 12
    k_chain_blur_lce<<<ga, dim3(256), 0, stream>>>(
        x, X2, gains, p_gamma, p_sb, p_hr, p_br, p_ct, p_enh, wk);

    // Kernel B: X2 -> OUT (blur + softness + gradient + clip)
    dim3 gb(WW / TW, HH / TH2, NPLANES);     // 16 x 8 x 12
    k_blur_final<<<gb, dim3(256), 0, stream>>>(
        X2, OUT, p_soft, p_int, p_rot, p_hard, wk);
}